// Round 1
// baseline (747.118 us; speedup 1.0000x reference)
//
#include <hip/hip_runtime.h>

#define N 16384
#define D 1024
#define EPSF 1e-8f

#define BM 128
#define BN 128
#define BK 64
#define NSPLIT 8
#define CTS ((N / BN) / NSPLIT) /* 16 column tiles per split */

typedef __attribute__((ext_vector_type(8))) short bf16x8;
typedef __attribute__((ext_vector_type(4))) float f32x4;
typedef unsigned int u32;
typedef unsigned long long u64;

// ---------- helpers ----------

__device__ __forceinline__ unsigned short f2bf(float f) {
  // round-to-nearest-even fp32 -> bf16
  u32 u = __float_as_uint(f);
  u32 r = (u + 0x7fffu + ((u >> 16) & 1u)) >> 16;
  return (unsigned short)r;
}

__device__ __forceinline__ void gload_lds16(const void* g, void* l) {
  // async global->LDS, 16B per lane; LDS dest = wave-uniform base + lane*16
  __builtin_amdgcn_global_load_lds(
      (const __attribute__((address_space(1))) u32*)g,
      (__attribute__((address_space(3))) u32*)l, 16, 0, 0);
}

// ---------- kernel 1: row L2 norms + bf16 normalized matrix ----------

__global__ __launch_bounds__(256) void k_normalize(
    const float* __restrict__ x, unsigned short* __restrict__ xnb,
    float* __restrict__ norms) {
  const int w = threadIdx.x >> 6, lane = threadIdx.x & 63;
  const int i = blockIdx.x * 4 + w;  // one wave per row
  const float4* xi = (const float4*)(x + (size_t)i * D);
  float4 v[4];
  float s = 0.f;
#pragma unroll
  for (int t = 0; t < 4; ++t) {
    v[t] = xi[lane + t * 64];
    s += v[t].x * v[t].x + v[t].y * v[t].y + v[t].z * v[t].z + v[t].w * v[t].w;
  }
#pragma unroll
  for (int sh = 32; sh; sh >>= 1) s += __shfl_xor(s, sh, 64);
  const float nrm = sqrtf(s);
  if (lane == 0) norms[i] = nrm;
  const float inv = 1.f / fmaxf(nrm, EPSF);
#pragma unroll
  for (int t = 0; t < 4; ++t) {
    ushort4 o;
    o.x = f2bf(v[t].x * inv);
    o.y = f2bf(v[t].y * inv);
    o.z = f2bf(v[t].z * inv);
    o.w = f2bf(v[t].w * inv);
    *(ushort4*)(xnb + (size_t)i * D + (size_t)(lane + t * 64) * 4) = o;
  }
}

// ---------- kernel 2: streaming bf16 MFMA similarity + running argmax ----------
// grid = (N/BM) * NSPLIT blocks; block = 256 threads = 4 waves (2x2 wave grid).
// Each block: rows [rowTile*128, +128), cols [split*2048, +2048) in 16 tiles.

__global__ __launch_bounds__(256) void k_argmax(
    const unsigned short* __restrict__ xnb, u64* __restrict__ best_out) {
  __shared__ __align__(16) unsigned char As[BM * BK * 2];  // 16 KB
  __shared__ __align__(16) unsigned char Bs[BN * BK * 2];  // 16 KB
  __shared__ u64 mrg[BM][2];

  const int tid = (int)threadIdx.x;
  const int lane = tid & 63;
  const int w = tid >> 6;
  const int wr = w >> 1, wc = w & 1;
  const int rowTile = (int)blockIdx.x >> 3;
  const int split = (int)blockIdx.x & 7;
  const int rowBase = rowTile * BM;

  // staging: chunk c covers rows c*8..c*8+7 of the tile, lane -> (row c*8+lane/8,
  // 16B at col-byte (lane%8)*16). LDS dest is linear; source col is pre-swizzled
  // with the same XOR the reader applies (rule: both-sides-or-neither).
  const int srow = lane >> 3;                          // row&7 of my 16B chunk
  const int scolB = ((lane & 7) << 4) ^ (srow << 4);   // swizzled source byte col

  float bestv[16];
  int bestc[16];
#pragma unroll
  for (int q = 0; q < 16; ++q) { bestv[q] = -2.f; bestc[q] = 0; }

  for (int ct = 0; ct < CTS; ++ct) {
    const int colTile = split * CTS + ct;
    const int colBase = colTile * BN;
    f32x4 acc[4][4];
#pragma unroll
    for (int m = 0; m < 4; ++m)
#pragma unroll
      for (int n = 0; n < 4; ++n) acc[m][n] = (f32x4){0.f, 0.f, 0.f, 0.f};

    for (int k0 = 0; k0 < D; k0 += BK) {
#pragma unroll
      for (int l = 0; l < 4; ++l) {
        const int c = l * 4 + w;           // 16 chunks of 8 rows each
        const int r = c * 8 + srow;
        gload_lds16(xnb + (size_t)(rowBase + r) * D + k0 + (scolB >> 1),
                    As + c * 1024);
        gload_lds16(xnb + (size_t)(colBase + r) * D + k0 + (scolB >> 1),
                    Bs + c * 1024);
      }
      __syncthreads();
#pragma unroll
      for (int kk = 0; kk < 2; ++kk) {
        bf16x8 af[4], bfr[4];
        const int krd = kk * 64 + ((lane >> 4) << 4);  // byte offset in 128B row
#pragma unroll
        for (int m = 0; m < 4; ++m) {
          const int row = wr * 64 + m * 16 + (lane & 15);
          af[m] = *(const bf16x8*)(As + row * 128 + (krd ^ ((row & 7) << 4)));
        }
#pragma unroll
        for (int n = 0; n < 4; ++n) {
          const int col = wc * 64 + n * 16 + (lane & 15);
          bfr[n] = *(const bf16x8*)(Bs + col * 128 + (krd ^ ((col & 7) << 4)));
        }
#pragma unroll
        for (int m = 0; m < 4; ++m)
#pragma unroll
          for (int n = 0; n < 4; ++n)
            acc[m][n] = __builtin_amdgcn_mfma_f32_16x16x32_bf16(
                af[m], bfr[n], acc[m][n], 0, 0, 0);
      }
      __syncthreads();
    }

    // running per-row best update (all-register, static indices)
    const bool diagT = (colTile == rowTile);
#pragma unroll
    for (int m = 0; m < 4; ++m) {
      const int rl0 = wr * 64 + m * 16 + ((lane >> 4) << 2);
#pragma unroll
      for (int n = 0; n < 4; ++n) {
        const int cl = wc * 64 + n * 16 + (lane & 15);
#pragma unroll
        for (int r = 0; r < 4; ++r) {
          float s = acc[m][n][r];
          if (diagT && (rl0 + r == cl)) s = -2.f;  // mask self-similarity
          const int q = m * 4 + r;
          if (s > bestv[q]) { bestv[q] = s; bestc[q] = colBase + cl; }
        }
      }
    }
  }

  // cross-lane reduce: the 16 lanes of each group (lane>>4) share rows.
#pragma unroll
  for (int m = 0; m < 4; ++m)
#pragma unroll
    for (int r = 0; r < 4; ++r) {
      const int q = m * 4 + r;
      u32 u = __float_as_uint(bestv[q]);
      u = (u & 0x80000000u) ? ~u : (u | 0x80000000u);  // monotone float->uint
      u64 p = ((u64)u << 32) | (u32)bestc[q];
#pragma unroll
      for (int sh = 1; sh < 16; sh <<= 1) {
        const u64 o = __shfl_xor(p, sh, 64);
        if (o > p) p = o;
      }
      if ((lane & 15) == 0) {
        const int rl = wr * 64 + m * 16 + ((lane >> 4) << 2) + r;
        mrg[rl][wc] = p;
      }
    }
  __syncthreads();
  if (tid < BM) {
    const u64 p0 = mrg[tid][0], p1 = mrg[tid][1];
    best_out[(size_t)(rowBase + tid) * NSPLIT + split] = p0 > p1 ? p0 : p1;
  }
}

// ---------- kernel 3: merge splits, exact fp32 distance + log ----------

__global__ __launch_bounds__(256) void k_dist(
    const float* __restrict__ x, const float* __restrict__ norms,
    const u64* __restrict__ best, float* __restrict__ logd) {
  const int w = threadIdx.x >> 6, lane = threadIdx.x & 63;
  const int i = blockIdx.x * 4 + w;
  u64 p = 0;
#pragma unroll
  for (int s = 0; s < NSPLIT; ++s) {
    const u64 q = best[(size_t)i * NSPLIT + s];
    if (q > p) p = q;
  }
  const int j = (int)(p & 0xffffffffu);
  const float invi = 1.f / fmaxf(norms[i], EPSF);
  const float invj = 1.f / fmaxf(norms[j], EPSF);
  const float4* xi = (const float4*)(x + (size_t)i * D);
  const float4* xj = (const float4*)(x + (size_t)j * D);
  float s = 0.f;
#pragma unroll
  for (int t = 0; t < 4; ++t) {
    const float4 a = xi[lane + t * 64], b = xj[lane + t * 64];
    float d;
    d = a.x * invi - b.x * invj + EPSF; s += d * d;
    d = a.y * invi - b.y * invj + EPSF; s += d * d;
    d = a.z * invi - b.z * invj + EPSF; s += d * d;
    d = a.w * invi - b.w * invj + EPSF; s += d * d;
  }
#pragma unroll
  for (int sh = 32; sh; sh >>= 1) s += __shfl_xor(s, sh, 64);
  if (lane == 0) logd[i] = logf(sqrtf(s) + EPSF);
}

// ---------- kernel 4: deterministic fixed-order mean ----------

__global__ __launch_bounds__(256) void k_final(const float* __restrict__ logd,
                                               float* __restrict__ out) {
  __shared__ double red[256];
  double s = 0.0;
  for (int i = threadIdx.x; i < N; i += 256) s += (double)logd[i];
  red[threadIdx.x] = s;
  __syncthreads();
  for (int sh = 128; sh; sh >>= 1) {
    if ((int)threadIdx.x < sh) red[threadIdx.x] += red[threadIdx.x + sh];
    __syncthreads();
  }
  if (threadIdx.x == 0) out[0] = (float)(-red[0] / (double)N);
}

// ---------- launch ----------

extern "C" void kernel_launch(void* const* d_in, const int* in_sizes, int n_in,
                              void* d_out, int out_size, void* d_ws,
                              size_t ws_size, hipStream_t stream) {
  const float* x = (const float*)d_in[0];
  float* out = (float*)d_out;
  char* ws = (char*)d_ws;

  // ws layout (all 64B-aligned):
  //   xnb   : N*D bf16          = 33554432 B
  //   norms : N f32             =    65536 B
  //   best  : N*NSPLIT u64      =  1048576 B
  //   logd  : N f32             =    65536 B   (total ~34.7 MB)
  unsigned short* xnb = (unsigned short*)ws;
  float* norms = (float*)(ws + 33554432);
  u64* best = (u64*)(ws + 33554432 + 65536);
  float* logd = (float*)(ws + 33554432 + 65536 + 1048576);

  k_normalize<<<N / 4, 256, 0, stream>>>(x, xnb, norms);
  k_argmax<<<(N / BM) * NSPLIT, 256, 0, stream>>>(xnb, best);
  k_dist<<<N / 4, 256, 0, stream>>>(x, norms, best, logd);
  k_final<<<1, 256, 0, stream>>>(logd, out);
}

// Round 2
// 545.028 us; speedup vs baseline: 1.3708x; 1.3708x over previous
//
#include <hip/hip_runtime.h>

#define N 16384
#define D 1024
#define EPSF 1e-8f
#define NSPLIT 4
#define CPS 4096 /* cols per split */
#define NCT 16   /* 256-wide col tiles per split */

typedef __attribute__((ext_vector_type(8))) short bf16x8;
typedef __attribute__((ext_vector_type(4))) float f32x4;
typedef unsigned int u32;
typedef unsigned long long u64;

// LDS map (bytes): A [0,64K) = [dbuf2][kh2][16K]; B [64K,128K); dummy [128K,144K); mrg [144K,+4K)
#define LDS_B 65536
#define LDS_DMY 131072
#define LDS_MRG 147456
#define LDS_TOT 151552

__device__ __forceinline__ unsigned short f2bf(float f) {
  u32 u = __float_as_uint(f);
  return (unsigned short)((u + 0x7fffu + ((u >> 16) & 1u)) >> 16);
}

__device__ __forceinline__ void gload_lds16(const void* g, void* l) {
  __builtin_amdgcn_global_load_lds(
      (const __attribute__((address_space(1))) u32*)g,
      (__attribute__((address_space(3))) u32*)l, 16, 0, 0);
}

// ---------- kernel 1: row L2 norms + bf16 normalized matrix ----------

__global__ __launch_bounds__(256) void k_normalize(
    const float* __restrict__ x, unsigned short* __restrict__ xnb,
    float* __restrict__ norms) {
  const int w = threadIdx.x >> 6, lane = threadIdx.x & 63;
  const int i = blockIdx.x * 4 + w;
  const float4* xi = (const float4*)(x + (size_t)i * D);
  float4 v[4];
  float s = 0.f;
#pragma unroll
  for (int t = 0; t < 4; ++t) {
    v[t] = xi[lane + t * 64];
    s += v[t].x * v[t].x + v[t].y * v[t].y + v[t].z * v[t].z + v[t].w * v[t].w;
  }
#pragma unroll
  for (int sh = 32; sh; sh >>= 1) s += __shfl_xor(s, sh, 64);
  const float nrm = sqrtf(s);
  if (lane == 0) norms[i] = nrm;
  const float inv = 1.f / fmaxf(nrm, EPSF);
#pragma unroll
  for (int t = 0; t < 4; ++t) {
    ushort4 o;
    o.x = f2bf(v[t].x * inv);
    o.y = f2bf(v[t].y * inv);
    o.z = f2bf(v[t].z * inv);
    o.w = f2bf(v[t].w * inv);
    *(ushort4*)(xnb + (size_t)i * D + (size_t)(lane + t * 64) * 4) = o;
  }
}

// ---------- kernel 2: 8-phase 256x256 streaming argmax GEMM ----------
// 512 thr = 8 waves (4M x 2N); per-wave C = 64x128. K-tile = 64, split into
// two 32-k halves per operand; 4 phases/K-tile; counted vmcnt(8); raw barriers.

__device__ __forceinline__ void stage(const char* xnbB, char* lds, int H,
                                      int rowBase, int split, int w,
                                      const int srcOff0, const int srcOff1) {
  char* regionD;
  size_t uB;
  if (H < 1024) {
    const int T = H >> 2, h = H & 3;
    const int ktl = T & 15, cts = T >> 4;
    const int kh = h >> 1;
    const int isB = h & 1;
    const int panel = isB ? split * CPS + cts * 256 : rowBase;
    regionD = lds + (isB ? LDS_B : 0) + (T & 1) * 32768 + kh * 16384;
    uB = (size_t)panel * 2048 + (size_t)(ktl * 128 + kh * 64);
  } else {
    regionD = lds + LDS_DMY;
    uB = 0;
  }
  gload_lds16(xnbB + uB + srcOff0, regionD + w * 1024);
  gload_lds16(xnbB + uB + srcOff1, regionD + 8192 + w * 1024);
}

#define PHASE(B_, KK_, NH_, VM_)                                               \
  do {                                                                         \
    if ((NH_) == 0) {                                                          \
      _Pragma("unroll") for (int m = 0; m < 4; ++m) a[m] =                     \
          *(const bf16x8*)(lds + ((B_)*32768 + (KK_)*16384) + aOff[m]);        \
    }                                                                          \
    bf16x8 b0 = *(const bf16x8*)(lds + ((B_)*32768 + (KK_)*16384) + bOff[(NH_)*4 + 0]); \
    bf16x8 b1 = *(const bf16x8*)(lds + ((B_)*32768 + (KK_)*16384) + bOff[(NH_)*4 + 1]); \
    bf16x8 b2 = *(const bf16x8*)(lds + ((B_)*32768 + (KK_)*16384) + bOff[(NH_)*4 + 2]); \
    bf16x8 b3 = *(const bf16x8*)(lds + ((B_)*32768 + (KK_)*16384) + bOff[(NH_)*4 + 3]); \
    stage(xnbB, lds, H, rowBase, split, w, srcOff0, srcOff1);                  \
    ++H;                                                                       \
    __builtin_amdgcn_s_barrier();                                              \
    asm volatile("s_waitcnt lgkmcnt(0)" ::: "memory");                         \
    __builtin_amdgcn_s_setprio(1);                                             \
    _Pragma("unroll") for (int m = 0; m < 4; ++m) {                            \
      acc[m][(NH_)*4 + 0] = __builtin_amdgcn_mfma_f32_16x16x32_bf16(           \
          a[m], b0, acc[m][(NH_)*4 + 0], 0, 0, 0);                             \
      acc[m][(NH_)*4 + 1] = __builtin_amdgcn_mfma_f32_16x16x32_bf16(           \
          a[m], b1, acc[m][(NH_)*4 + 1], 0, 0, 0);                             \
      acc[m][(NH_)*4 + 2] = __builtin_amdgcn_mfma_f32_16x16x32_bf16(           \
          a[m], b2, acc[m][(NH_)*4 + 2], 0, 0, 0);                             \
      acc[m][(NH_)*4 + 3] = __builtin_amdgcn_mfma_f32_16x16x32_bf16(           \
          a[m], b3, acc[m][(NH_)*4 + 3], 0, 0, 0);                             \
    }                                                                          \
    __builtin_amdgcn_s_setprio(0);                                             \
    if (VM_) asm volatile("s_waitcnt vmcnt(8)" ::: "memory");                  \
    __builtin_amdgcn_s_barrier();                                              \
    asm volatile("" ::: "memory");                                             \
  } while (0)

__global__ __launch_bounds__(512, 2) void k_argmax(
    const unsigned short* __restrict__ xnb, u64* __restrict__ best_out) {
  extern __shared__ char lds[];
  const char* xnbB = (const char*)xnb;
  const int tid = (int)threadIdx.x, lane = tid & 63, w = tid >> 6;
  const int wr = w >> 1, wc = w & 1;
  const int rowTile = (int)blockIdx.x >> 2;
  const int split = (int)blockIdx.x & 3;
  const int rowBase = rowTile * 256;

  // swizzled LDS read offsets: logical (row rr, 16B granule q) ->
  // line=rr>>1, inner = (((rr&1)<<6)|(q<<4)) ^ ((line&7)<<4)
  int aOff[4], bOff[8];
  {
    const int q = lane >> 4, li = lane & 15;
#pragma unroll
    for (int m = 0; m < 4; ++m) {
      const int rr = wr * 64 + m * 16 + li;
      const int line = rr >> 1;
      aOff[m] = line * 128 + ((((rr & 1) << 6) | (q << 4)) ^ ((line & 7) << 4));
    }
#pragma unroll
    for (int nf = 0; nf < 8; ++nf) {
      const int rr = wc * 128 + nf * 16 + li;
      const int line = rr >> 1;
      bOff[nf] = LDS_B + line * 128 +
                 ((((rr & 1) << 6) | (q << 4)) ^ ((line & 7) << 4));
    }
  }
  // staging source offsets: invert the swizzle for linear global_load_lds dest
  int srcOff0, srcOff1;
#pragma unroll
  for (int qq = 0; qq < 2; ++qq) {
    const int G = qq * 512 + w * 64 + lane;  // linear 16B granule in region
    const int line = G >> 3;
    const int innerLog = ((G & 7) << 4) ^ ((line & 7) << 4);
    const int r = (line << 1) | (innerLog >> 6);
    const int qlog = (innerLog >> 4) & 3;
    const int so = r * 2048 + qlog * 16;
    if (qq == 0) srcOff0 = so; else srcOff1 = so;
  }

  float bestv[16];
  int bestc[16];
#pragma unroll
  for (int i = 0; i < 16; ++i) {
    bestv[i] = -2.f;
    bestc[i] = 0;
  }
  const int rB2 = wr * 64 + ((lane >> 4) << 2);
  const int cB2 = wc * 128 + (lane & 15);

  int H = 0;
  for (int i = 0; i < 6; ++i) {
    stage(xnbB, lds, H, rowBase, split, w, srcOff0, srcOff1);
    ++H;
  }
  asm volatile("s_waitcnt vmcnt(8)" ::: "memory");
  __builtin_amdgcn_s_barrier();
  asm volatile("" ::: "memory");

  f32x4 acc[4][8];
  bf16x8 a[4];
  for (int ct = 0; ct < NCT; ++ct) {
#pragma unroll
    for (int m = 0; m < 4; ++m)
#pragma unroll
      for (int n = 0; n < 8; ++n) acc[m][n] = (f32x4){0.f, 0.f, 0.f, 0.f};

    for (int it = 0; it < 8; ++it) {  // 2 K-tiles per iteration, 8 phases
      PHASE(0, 0, 0, 0);
      PHASE(0, 0, 1, 1);
      PHASE(0, 1, 0, 0);
      PHASE(0, 1, 1, 1);
      PHASE(1, 0, 0, 0);
      PHASE(1, 0, 1, 1);
      PHASE(1, 1, 0, 0);
      PHASE(1, 1, 1, 1);
    }

    const int colBase = split * CPS + ct * 256;
    const bool diag = (colBase == rowBase);
#pragma unroll
    for (int m = 0; m < 4; ++m)
#pragma unroll
      for (int nf = 0; nf < 8; ++nf)
#pragma unroll
        for (int r = 0; r < 4; ++r) {
          float s = acc[m][nf][r];
          if (diag && (rB2 + m * 16 + r == cB2 + nf * 16)) s = -2.f;
          const int qs = m * 4 + r;
          if (s > bestv[qs]) {
            bestv[qs] = s;
            bestc[qs] = colBase + cB2 + nf * 16;
          }
        }
  }

  // reduce across the 16 lanes sharing each row, then across wc via LDS
  u64* mrg = (u64*)(lds + LDS_MRG);
#pragma unroll
  for (int m = 0; m < 4; ++m)
#pragma unroll
    for (int r = 0; r < 4; ++r) {
      const int qs = m * 4 + r;
      u32 u = __float_as_uint(bestv[qs]);
      u = (u & 0x80000000u) ? ~u : (u | 0x80000000u);
      u64 p = ((u64)u << 32) | (u32)bestc[qs];
#pragma unroll
      for (int sh = 1; sh < 16; sh <<= 1) {
        const u64 o = __shfl_xor(p, sh, 64);
        if (o > p) p = o;
      }
      if ((lane & 15) == 0) mrg[(rB2 + m * 16 + r) * 2 + wc] = p;
    }
  __syncthreads();
  if (tid < 256) {
    const u64 p0 = mrg[tid * 2], p1 = mrg[tid * 2 + 1];
    best_out[(size_t)(rowBase + tid) * NSPLIT + split] = p0 > p1 ? p0 : p1;
  }
}

// ---------- kernel 3: merge splits, exact fp32 distance + log ----------

__global__ __launch_bounds__(256) void k_dist(
    const float* __restrict__ x, const float* __restrict__ norms,
    const u64* __restrict__ best, float* __restrict__ logd) {
  const int w = threadIdx.x >> 6, lane = threadIdx.x & 63;
  const int i = blockIdx.x * 4 + w;
  u64 p = 0;
#pragma unroll
  for (int s = 0; s < NSPLIT; ++s) {
    const u64 q = best[(size_t)i * NSPLIT + s];
    if (q > p) p = q;
  }
  const int j = (int)(p & 0xffffffffu);
  const float invi = 1.f / fmaxf(norms[i], EPSF);
  const float invj = 1.f / fmaxf(norms[j], EPSF);
  const float4* xi = (const float4*)(x + (size_t)i * D);
  const float4* xj = (const float4*)(x + (size_t)j * D);
  float s = 0.f;
#pragma unroll
  for (int t = 0; t < 4; ++t) {
    const float4 a = xi[lane + t * 64], b = xj[lane + t * 64];
    float d;
    d = a.x * invi - b.x * invj + EPSF; s += d * d;
    d = a.y * invi - b.y * invj + EPSF; s += d * d;
    d = a.z * invi - b.z * invj + EPSF; s += d * d;
    d = a.w * invi - b.w * invj + EPSF; s += d * d;
  }
#pragma unroll
  for (int sh = 32; sh; sh >>= 1) s += __shfl_xor(s, sh, 64);
  if (lane == 0) logd[i] = logf(sqrtf(s) + EPSF);
}

// ---------- kernel 4: deterministic fixed-order mean ----------

__global__ __launch_bounds__(256) void k_final(const float* __restrict__ logd,
                                               float* __restrict__ out) {
  __shared__ double red[256];
  double s = 0.0;
  for (int i = threadIdx.x; i < N; i += 256) s += (double)logd[i];
  red[threadIdx.x] = s;
  __syncthreads();
  for (int sh = 128; sh; sh >>= 1) {
    if ((int)threadIdx.x < sh) red[threadIdx.x] += red[threadIdx.x + sh];
    __syncthreads();
  }
  if (threadIdx.x == 0) out[0] = (float)(-red[0] / (double)N);
}

// ---------- launch ----------

extern "C" void kernel_launch(void* const* d_in, const int* in_sizes, int n_in,
                              void* d_out, int out_size, void* d_ws,
                              size_t ws_size, hipStream_t stream) {
  const float* x = (const float*)d_in[0];
  float* out = (float*)d_out;
  char* ws = (char*)d_ws;

  // ws: xnb 32MB | norms 64KB | best N*NSPLIT*8 = 512KB | logd 64KB
  unsigned short* xnb = (unsigned short*)ws;
  float* norms = (float*)(ws + 33554432);
  u64* best = (u64*)(ws + 33619968);
  float* logd = (float*)(ws + 34144256);

  k_normalize<<<N / 4, 256, 0, stream>>>(x, xnb, norms);
  k_argmax<<<64 * NSPLIT, 512, LDS_TOT, stream>>>(xnb, best);
  k_dist<<<N / 4, 256, 0, stream>>>(x, norms, best, logd);
  k_final<<<1, 256, 0, stream>>>(logd, out);
}

// Round 3
// 308.148 us; speedup vs baseline: 2.4245x; 1.7687x over previous
//
#include <hip/hip_runtime.h>

#define N 16384
#define D 1024
#define EPSF 1e-8f
#define NSPLIT 4
#define CPS 4096 /* cols per split */
#define NCT 16   /* 256-wide col tiles per split */

typedef __attribute__((ext_vector_type(4))) int i32x4;
typedef unsigned int u32;
typedef unsigned long long u64;

// LDS (bytes): A ring4 [0,64K) = 4 bufs x 16KB; B ring4 [64K,128K); mrg [128K,+4K)
#define LDS_Bb 65536
#define LDS_MRG 131072
#define LDS_TOT 135168

__device__ __forceinline__ void gload_lds16(const void* g, void* l) {
  __builtin_amdgcn_global_load_lds(
      (const __attribute__((address_space(1))) u32*)g,
      (__attribute__((address_space(3))) u32*)l, 16, 0, 0);
}

// ---------- kernel 1: row L2 norms + per-row-scaled i8 matrix ----------

__global__ __launch_bounds__(256) void k_normalize(
    const float* __restrict__ x, signed char* __restrict__ xq,
    float* __restrict__ norms, float* __restrict__ colsc) {
  const int w = threadIdx.x >> 6, lane = threadIdx.x & 63;
  const int i = blockIdx.x * 4 + w;  // one wave per row
  const float4* xi = (const float4*)(x + (size_t)i * D);
  float4 v[4];
  float s = 0.f, mx = 0.f;
#pragma unroll
  for (int t = 0; t < 4; ++t) {
    v[t] = xi[lane + t * 64];
    s += v[t].x * v[t].x + v[t].y * v[t].y + v[t].z * v[t].z + v[t].w * v[t].w;
    mx = fmaxf(mx, fmaxf(fmaxf(fabsf(v[t].x), fabsf(v[t].y)),
                         fmaxf(fabsf(v[t].z), fabsf(v[t].w))));
  }
#pragma unroll
  for (int sh = 32; sh; sh >>= 1) {
    s += __shfl_xor(s, sh, 64);
    mx = fmaxf(mx, __shfl_xor(mx, sh, 64));
  }
  mx = fmaxf(mx, 1e-30f);
  const float nrm = sqrtf(s);
  const float inv = 1.f / fmaxf(nrm, EPSF);
  if (lane == 0) {
    norms[i] = nrm;
    colsc[i] = mx * inv;  // max |xn| of this row (positive)
  }
  const float qs = 127.f / mx;  // xn*127/max|xn| == v*qs
  u32* xo = (u32*)(xq + (size_t)i * D);
#pragma unroll
  for (int t = 0; t < 4; ++t) {
    const int q0 = __float2int_rn(v[t].x * qs);
    const int q1 = __float2int_rn(v[t].y * qs);
    const int q2 = __float2int_rn(v[t].z * qs);
    const int q3 = __float2int_rn(v[t].w * qs);
    xo[lane + t * 64] = (u32)(q0 & 0xff) | ((u32)(q1 & 0xff) << 8) |
                        ((u32)(q2 & 0xff) << 16) | ((u32)(q3 & 0xff) << 24);
  }
}

// ---------- kernel 2: i8 MFMA streaming argmax, ring-4 LDS pipeline ----------
// 256 blocks (64 rowTiles x 4 splits), 512 thr = 8 waves (4M x 2N),
// per-wave C = 64x128. K-tile = 64 k (one mfma_i32_16x16x64_i8 per frag pair).
// Ring-4 K-tile buffers; stage cursor runs 3 tiles ahead; 1 vmcnt(8)/K-tile.

// per-phase stage: 1 gload pair (8KB each half)
#define SG(gaddr, daddr) \
  gload_lds16(xqB + (gaddr) + srcLane, lds + (daddr) + w * 1024)

#define KT(KIDX, BUFC)                                                         \
  {                                                                            \
    const int ts = ct * 16 + (KIDX) + 3; /* stage target tile */               \
    const int ktl = ts & 15;                                                   \
    const int ctsw = (ts >> 4) & 15;                                           \
    const size_t aG = (size_t)rowBase * 1024 + (size_t)(ktl * 64);             \
    const size_t bG = (size_t)(split * CPS + ctsw * 256) * 1024 +              \
                      (size_t)(ktl * 64);                                      \
    i32x4 aa[4], bb[4];                                                        \
    _Pragma("unroll") for (int m = 0; m < 4; ++m) aa[m] =                      \
        *(const i32x4*)(lds + (BUFC)*16384 + aOff[m]);                         \
    _Pragma("unroll") for (int n = 0; n < 4; ++n) bb[n] =                      \
        *(const i32x4*)(lds + LDS_Bb + (BUFC)*16384 + bOff[n]);                \
    SG(aG, (((BUFC) + 3) & 3) * 16384);                                        \
    SG(aG + 131072, (((BUFC) + 3) & 3) * 16384 + 8192);                        \
    __builtin_amdgcn_s_barrier();                                              \
    asm volatile("s_waitcnt lgkmcnt(0)" ::: "memory");                         \
    __builtin_amdgcn_s_setprio(1);                                             \
    _Pragma("unroll") for (int m = 0; m < 4; ++m) {                            \
      _Pragma("unroll") for (int n = 0; n < 4; ++n) acc[m][n] =                \
          __builtin_amdgcn_mfma_i32_16x16x64_i8(aa[m], bb[n], acc[m][n], 0, 0, \
                                                0);                            \
    }                                                                          \
    __builtin_amdgcn_s_setprio(0);                                             \
    __builtin_amdgcn_s_barrier();                                              \
    _Pragma("unroll") for (int n = 0; n < 4; ++n) bb[n] =                      \
        *(const i32x4*)(lds + LDS_Bb + (BUFC)*16384 + bOff[4 + n]);            \
    SG(bG, LDS_Bb + (((BUFC) + 3) & 3) * 16384);                               \
    SG(bG + 131072, LDS_Bb + (((BUFC) + 3) & 3) * 16384 + 8192);               \
    __builtin_amdgcn_s_barrier();                                              \
    asm volatile("s_waitcnt lgkmcnt(0)" ::: "memory");                         \
    __builtin_amdgcn_s_setprio(1);                                             \
    _Pragma("unroll") for (int m = 0; m < 4; ++m) {                            \
      _Pragma("unroll") for (int n = 0; n < 4; ++n) acc[m][4 + n] =            \
          __builtin_amdgcn_mfma_i32_16x16x64_i8(aa[m], bb[n], acc[m][4 + n],   \
                                                0, 0, 0);                      \
    }                                                                          \
    __builtin_amdgcn_s_setprio(0);                                             \
    asm volatile("s_waitcnt vmcnt(8)" ::: "memory");                           \
    __builtin_amdgcn_s_barrier();                                              \
    asm volatile("" ::: "memory");                                             \
  }

__global__ __launch_bounds__(512, 2) void k_argmax(
    const signed char* __restrict__ xq, const float* __restrict__ colsc,
    u64* __restrict__ best_out) {
  extern __shared__ char lds[];
  const char* xqB = (const char*)xq;
  const int tid = (int)threadIdx.x, lane = tid & 63, w = tid >> 6;
  const int wr = w >> 1, wc = w & 1;
  const int rowTile = (int)blockIdx.x >> 2;
  const int split = (int)blockIdx.x & 3;
  const int rowBase = rowTile * 256;

  // LDS region layout: 256 rows x 64B (one K-tile window), 2 rows/128B line,
  // granule swizzle: inner = (((rr&1)<<6)|(q<<4)) ^ ((line&7)<<4)
  int aOff[4], bOff[8];
  const int q = lane >> 4, li = lane & 15;
#pragma unroll
  for (int m = 0; m < 4; ++m) {
    const int rr = wr * 64 + m * 16 + li;
    const int line = rr >> 1;
    aOff[m] = line * 128 + ((((rr & 1) << 6) | (q << 4)) ^ ((line & 7) << 4));
  }
#pragma unroll
  for (int nf = 0; nf < 8; ++nf) {
    const int rr = wc * 128 + nf * 16 + li;
    const int line = rr >> 1;
    bOff[nf] = line * 128 + ((((rr & 1) << 6) | (q << 4)) ^ ((line & 7) << 4));
  }
  // staging per-lane source offset (inverse swizzle; linear gload dest)
  const int posx = (lane & 7) ^ (lane >> 3);
  const int rrl = ((w * 8 + (lane >> 3)) << 1) | (posx >> 2);
  const int srcLane = rrl * 1024 + (posx & 3) * 16;

  float bestv[16];
  int bestc[16];
#pragma unroll
  for (int i = 0; i < 16; ++i) {
    bestv[i] = -3.0e38f;
    bestc[i] = 0;
  }
  const int rB2 = wr * 64 + (q << 2);
  const int cB2 = wc * 128 + li;

  // prologue: stage tiles 0..2 (A pair then B pair each), wait tile 0
  for (int p = 0; p < 3; ++p) {
    const size_t aG = (size_t)rowBase * 1024 + (size_t)(p * 64);
    const size_t bG = (size_t)(split * CPS) * 1024 + (size_t)(p * 64);
    SG(aG, p * 16384);
    SG(aG + 131072, p * 16384 + 8192);
    SG(bG, LDS_Bb + p * 16384);
    SG(bG + 131072, LDS_Bb + p * 16384 + 8192);
  }
  asm volatile("s_waitcnt vmcnt(8)" ::: "memory");
  __builtin_amdgcn_s_barrier();
  asm volatile("" ::: "memory");

  i32x4 acc[4][8];
  for (int ct = 0; ct < NCT; ++ct) {
#pragma unroll
    for (int m = 0; m < 4; ++m)
#pragma unroll
      for (int n = 0; n < 8; ++n) acc[m][n] = (i32x4){0, 0, 0, 0};

    for (int kq = 0; kq < 4; ++kq) {
      KT(kq * 4 + 0, 0);
      KT(kq * 4 + 1, 1);
      KT(kq * 4 + 2, 2);
      KT(kq * 4 + 3, 3);
    }

    const int colBase = split * CPS + ct * 256;
    float csc[8];
#pragma unroll
    for (int nf = 0; nf < 8; ++nf) csc[nf] = colsc[colBase + cB2 + nf * 16];
    const bool diag = (colBase == rowBase);
#pragma unroll
    for (int m = 0; m < 4; ++m)
#pragma unroll
      for (int nf = 0; nf < 8; ++nf)
#pragma unroll
        for (int r = 0; r < 4; ++r) {
          float v = (float)acc[m][nf][r] * csc[nf];
          if (diag && (rB2 + m * 16 + r == cB2 + nf * 16)) v = -3.0e38f;
          const int qs = m * 4 + r;
          if (v > bestv[qs]) {
            bestv[qs] = v;
            bestc[qs] = colBase + cB2 + nf * 16;
          }
        }
  }

  // reduce across the 16 lanes sharing each row, then across wc via LDS
  u64* mrg = (u64*)(lds + LDS_MRG);
#pragma unroll
  for (int m = 0; m < 4; ++m)
#pragma unroll
    for (int r = 0; r < 4; ++r) {
      const int qs = m * 4 + r;
      u32 u = __float_as_uint(bestv[qs]);
      u = (u & 0x80000000u) ? ~u : (u | 0x80000000u);
      u64 p = ((u64)u << 32) | (u32)bestc[qs];
#pragma unroll
      for (int sh = 1; sh < 16; sh <<= 1) {
        const u64 o = __shfl_xor(p, sh, 64);
        if (o > p) p = o;
      }
      if ((lane & 15) == 0) mrg[(rB2 + m * 16 + r) * 2 + wc] = p;
    }
  __syncthreads();
  if (tid < 256) {
    const u64 p0 = mrg[tid * 2], p1 = mrg[tid * 2 + 1];
    best_out[(size_t)(rowBase + tid) * NSPLIT + split] = p0 > p1 ? p0 : p1;
  }
}

// ---------- kernel 3: merge splits, exact fp32 distance + log ----------

__global__ __launch_bounds__(256) void k_dist(
    const float* __restrict__ x, const float* __restrict__ norms,
    const u64* __restrict__ best, float* __restrict__ logd) {
  const int w = threadIdx.x >> 6, lane = threadIdx.x & 63;
  const int i = blockIdx.x * 4 + w;
  u64 p = 0;
#pragma unroll
  for (int s = 0; s < NSPLIT; ++s) {
    const u64 qq = best[(size_t)i * NSPLIT + s];
    if (qq > p) p = qq;
  }
  const int j = (int)(p & 0xffffffffu);
  const float invi = 1.f / fmaxf(norms[i], EPSF);
  const float invj = 1.f / fmaxf(norms[j], EPSF);
  const float4* xi = (const float4*)(x + (size_t)i * D);
  const float4* xj = (const float4*)(x + (size_t)j * D);
  float s = 0.f;
#pragma unroll
  for (int t = 0; t < 4; ++t) {
    const float4 a = xi[lane + t * 64], b = xj[lane + t * 64];
    float d;
    d = a.x * invi - b.x * invj + EPSF; s += d * d;
    d = a.y * invi - b.y * invj + EPSF; s += d * d;
    d = a.z * invi - b.z * invj + EPSF; s += d * d;
    d = a.w * invi - b.w * invj + EPSF; s += d * d;
  }
#pragma unroll
  for (int sh = 32; sh; sh >>= 1) s += __shfl_xor(s, sh, 64);
  if (lane == 0) logd[i] = logf(sqrtf(s) + EPSF);
}

// ---------- kernel 4: deterministic fixed-order mean ----------

__global__ __launch_bounds__(256) void k_final(const float* __restrict__ logd,
                                               float* __restrict__ out) {
  __shared__ double red[256];
  double s = 0.0;
  for (int i = threadIdx.x; i < N; i += 256) s += (double)logd[i];
  red[threadIdx.x] = s;
  __syncthreads();
  for (int sh = 128; sh; sh >>= 1) {
    if ((int)threadIdx.x < sh) red[threadIdx.x] += red[threadIdx.x + sh];
    __syncthreads();
  }
  if (threadIdx.x == 0) out[0] = (float)(-red[0] / (double)N);
}

// ---------- launch ----------

extern "C" void kernel_launch(void* const* d_in, const int* in_sizes, int n_in,
                              void* d_out, int out_size, void* d_ws,
                              size_t ws_size, hipStream_t stream) {
  const float* x = (const float*)d_in[0];
  float* out = (float*)d_out;
  char* ws = (char*)d_ws;

  // ws: xq 16MB | norms 64KB | colsc 64KB | best 512KB | logd 64KB
  signed char* xq = (signed char*)ws;
  float* norms = (float*)(ws + 16777216);
  float* colsc = (float*)(ws + 16842752);
  u64* best = (u64*)(ws + 16908288);
  float* logd = (float*)(ws + 17432576);

  k_normalize<<<N / 4, 256, 0, stream>>>(x, xq, norms, colsc);
  k_argmax<<<64 * NSPLIT, 512, LDS_TOT, stream>>>(xq, colsc, best);
  k_dist<<<N / 4, 256, 0, stream>>>(x, norms, best, logd);
  k_final<<<1, 256, 0, stream>>>(logd, out);
}

// Round 4
// 290.589 us; speedup vs baseline: 2.5710x; 1.0604x over previous
//
#include <hip/hip_runtime.h>

#define N 16384
#define D 1024
#define EPSF 1e-8f
#define NSPLIT 4
#define CPS 4096 /* cols per split */
#define NCT 16   /* 256-wide col tiles per split */
#define QSCALE 448.0f

typedef __attribute__((ext_vector_type(4))) int i32x4;
typedef unsigned int u32;
typedef unsigned long long u64;

// LDS (bytes): A ring4 [0,64K) = 4 bufs x 16KB; B ring4 [64K,128K); mrg [128K,+4K)
#define LDS_Bb 65536
#define LDS_MRG 131072
#define LDS_TOT 135168

__device__ __forceinline__ void gload_lds16(const void* g, void* l) {
  __builtin_amdgcn_global_load_lds(
      (const __attribute__((address_space(1))) u32*)g,
      (__attribute__((address_space(3))) u32*)l, 16, 0, 0);
}

// ---------- kernel 1: row L2 norms + globally-scaled i8 matrix ----------

__global__ __launch_bounds__(256) void k_normalize(
    const float* __restrict__ x, signed char* __restrict__ xq,
    float* __restrict__ norms) {
  const int w = threadIdx.x >> 6, lane = threadIdx.x & 63;
  const int i = blockIdx.x * 4 + w;  // one wave per row
  const float4* xi = (const float4*)(x + (size_t)i * D);
  float4 v[4];
  float s = 0.f;
#pragma unroll
  for (int t = 0; t < 4; ++t) {
    v[t] = xi[lane + t * 64];
    s += v[t].x * v[t].x + v[t].y * v[t].y + v[t].z * v[t].z + v[t].w * v[t].w;
  }
#pragma unroll
  for (int sh = 32; sh; sh >>= 1) s += __shfl_xor(s, sh, 64);
  const float nrm = sqrtf(s);
  if (lane == 0) norms[i] = nrm;
  const float qs = QSCALE / fmaxf(nrm, EPSF);  // global scale: q = xn*QSCALE
  u32* xo = (u32*)(xq + (size_t)i * D);
#pragma unroll
  for (int t = 0; t < 4; ++t) {
    const int q0 = __float2int_rn(fminf(fmaxf(v[t].x * qs, -127.f), 127.f));
    const int q1 = __float2int_rn(fminf(fmaxf(v[t].y * qs, -127.f), 127.f));
    const int q2 = __float2int_rn(fminf(fmaxf(v[t].z * qs, -127.f), 127.f));
    const int q3 = __float2int_rn(fminf(fmaxf(v[t].w * qs, -127.f), 127.f));
    xo[lane + t * 64] = (u32)(q0 & 0xff) | ((u32)(q1 & 0xff) << 8) |
                        ((u32)(q2 & 0xff) << 16) | ((u32)(q3 & 0xff) << 24);
  }
}

// ---------- kernel 2: i8 MFMA streaming argmax, ring-4, compiler-scheduled ----------
// 256 blocks (64 rowTiles x 4 splits), 512 thr = 8 waves (4M x 2N),
// per-wave C = 64x128. K-tile = 64 k. Ring-4 buffers, stage 3 tiles ahead,
// one counted vmcnt(8) per K-tile, ONE barrier per phase, NO lgkm pin:
// plain C++ ds_reads let the compiler interleave counted lgkmcnt with MFMAs.

#define SG(gaddr, daddr) \
  gload_lds16(xqB + (gaddr) + srcLane, lds + (daddr) + w * 1024)

#define KT(KIDX, BUFC)                                                         \
  {                                                                            \
    const int ts = ct * 16 + (KIDX) + 3; /* stage target tile */               \
    const int ktl = ts & 15;                                                   \
    const int ctsw = (ts >> 4) & 15;                                           \
    const size_t aG = (size_t)rowBase * 1024 + (size_t)(ktl * 64);             \
    const size_t bG = (size_t)(split * CPS + ctsw * 256) * 1024 +              \
                      (size_t)(ktl * 64);                                      \
    i32x4 aa[4], bb[4];                                                        \
    _Pragma("unroll") for (int m = 0; m < 4; ++m) aa[m] =                      \
        *(const i32x4*)(lds + (BUFC)*16384 + aOff[m]);                         \
    _Pragma("unroll") for (int n = 0; n < 4; ++n) bb[n] =                      \
        *(const i32x4*)(lds + LDS_Bb + (BUFC)*16384 + bOff[n]);                \
    SG(aG, (((BUFC) + 3) & 3) * 16384);                                        \
    SG(aG + 131072, (((BUFC) + 3) & 3) * 16384 + 8192);                        \
    __builtin_amdgcn_s_setprio(1);                                             \
    _Pragma("unroll") for (int m = 0; m < 4; ++m) {                            \
      _Pragma("unroll") for (int n = 0; n < 4; ++n) acc[m][n] =                \
          __builtin_amdgcn_mfma_i32_16x16x64_i8(aa[m], bb[n], acc[m][n], 0, 0, \
                                                0);                            \
    }                                                                          \
    __builtin_amdgcn_s_setprio(0);                                             \
    __builtin_amdgcn_s_barrier();                                              \
    asm volatile("" ::: "memory");                                             \
    _Pragma("unroll") for (int n = 0; n < 4; ++n) bb[n] =                      \
        *(const i32x4*)(lds + LDS_Bb + (BUFC)*16384 + bOff[4 + n]);            \
    SG(bG, LDS_Bb + (((BUFC) + 3) & 3) * 16384);                               \
    SG(bG + 131072, LDS_Bb + (((BUFC) + 3) & 3) * 16384 + 8192);               \
    __builtin_amdgcn_s_setprio(1);                                             \
    _Pragma("unroll") for (int m = 0; m < 4; ++m) {                            \
      _Pragma("unroll") for (int n = 0; n < 4; ++n) acc[m][4 + n] =            \
          __builtin_amdgcn_mfma_i32_16x16x64_i8(aa[m], bb[n], acc[m][4 + n],   \
                                                0, 0, 0);                      \
    }                                                                          \
    __builtin_amdgcn_s_setprio(0);                                             \
    asm volatile("s_waitcnt vmcnt(8)" ::: "memory");                           \
    __builtin_amdgcn_s_barrier();                                              \
    asm volatile("" ::: "memory");                                             \
  }

__global__ __launch_bounds__(512, 2) void k_argmax(
    const signed char* __restrict__ xq, u64* __restrict__ best_out) {
  extern __shared__ char lds[];
  const char* xqB = (const char*)xq;
  const int tid = (int)threadIdx.x, lane = tid & 63, w = tid >> 6;
  const int wr = w >> 1, wc = w & 1;
  const int rowTile = (int)blockIdx.x >> 2;
  const int split = (int)blockIdx.x & 3;
  const int rowBase = rowTile * 256;

  // LDS region: 256 rows x 64B K-tile window, 2 rows/128B line,
  // granule swizzle: inner = (((rr&1)<<6)|(q<<4)) ^ ((line&7)<<4)
  int aOff[4], bOff[8];
  const int q = lane >> 4, li = lane & 15;
#pragma unroll
  for (int m = 0; m < 4; ++m) {
    const int rr = wr * 64 + m * 16 + li;
    const int line = rr >> 1;
    aOff[m] = line * 128 + ((((rr & 1) << 6) | (q << 4)) ^ ((line & 7) << 4));
  }
#pragma unroll
  for (int nf = 0; nf < 8; ++nf) {
    const int rr = wc * 128 + nf * 16 + li;
    const int line = rr >> 1;
    bOff[nf] = line * 128 + ((((rr & 1) << 6) | (q << 4)) ^ ((line & 7) << 4));
  }
  // staging per-lane source offset (inverse swizzle; linear gload dest)
  const int posx = (lane & 7) ^ (lane >> 3);
  const int rrl = ((w * 8 + (lane >> 3)) << 1) | (posx >> 2);
  const int srcLane = rrl * 1024 + (posx & 3) * 16;

  int bestp[16];  // packed (dot<<3)|nf, int-ordered
  int bestc[16];
#pragma unroll
  for (int i = 0; i < 16; ++i) {
    bestp[i] = (int)0x80000000;
    bestc[i] = 0;
  }
  const int rB2 = wr * 64 + (q << 2);
  const int cB2 = wc * 128 + li;

  // prologue: stage tiles 0..2, wait tile 0 (8 newest may stay in flight)
  for (int p = 0; p < 3; ++p) {
    const size_t aG = (size_t)rowBase * 1024 + (size_t)(p * 64);
    const size_t bG = (size_t)(split * CPS) * 1024 + (size_t)(p * 64);
    SG(aG, p * 16384);
    SG(aG + 131072, p * 16384 + 8192);
    SG(bG, LDS_Bb + p * 16384);
    SG(bG + 131072, LDS_Bb + p * 16384 + 8192);
  }
  asm volatile("s_waitcnt vmcnt(8)" ::: "memory");
  __builtin_amdgcn_s_barrier();
  asm volatile("" ::: "memory");

  i32x4 acc[4][8];
  for (int ct = 0; ct < NCT; ++ct) {
#pragma unroll
    for (int m = 0; m < 4; ++m)
#pragma unroll
      for (int n = 0; n < 8; ++n) acc[m][n] = (i32x4){0, 0, 0, 0};

    for (int kq = 0; kq < 4; ++kq) {
      KT(kq * 4 + 0, 0);
      KT(kq * 4 + 1, 1);
      KT(kq * 4 + 2, 2);
      KT(kq * 4 + 3, 3);
    }

    const int colBase = split * CPS + ct * 256;
    if (colBase == rowBase) {  // diagonal tile: mask self before max-fold
#pragma unroll
      for (int m = 0; m < 4; ++m)
#pragma unroll
        for (int r = 0; r < 4; ++r) {
          const int qs = m * 4 + r;
          const int grow = rB2 + m * 16 + r;
          int pm = bestp[qs];
#pragma unroll
          for (int nf = 0; nf < 8; ++nf) {
            int pv = (int)(((u32)acc[m][nf][r] << 3) | (u32)nf);
            if (grow == cB2 + nf * 16) pv = (int)0x80000000;
            pm = pm > pv ? pm : pv;
          }
          if (pm > bestp[qs]) {
            bestp[qs] = pm;
            bestc[qs] = colBase + cB2 + ((pm & 7) << 4);
          }
        }
    } else {
#pragma unroll
      for (int m = 0; m < 4; ++m)
#pragma unroll
        for (int r = 0; r < 4; ++r) {
          const int qs = m * 4 + r;
          int pm = (int)(((u32)acc[m][0][r] << 3));
#pragma unroll
          for (int nf = 1; nf < 8; ++nf) {
            const int pv = (int)(((u32)acc[m][nf][r] << 3) | (u32)nf);
            pm = pm > pv ? pm : pv;
          }
          if (pm > bestp[qs]) {
            bestp[qs] = pm;
            bestc[qs] = colBase + cB2 + ((pm & 7) << 4);
          }
        }
    }
  }

  // reduce across the 16 lanes sharing each row, then across wc via LDS
  u64* mrg = (u64*)(lds + LDS_MRG);
#pragma unroll
  for (int m = 0; m < 4; ++m)
#pragma unroll
    for (int r = 0; r < 4; ++r) {
      const int qs = m * 4 + r;
      const u32 mono = (u32)bestp[qs] ^ 0x80000000u;  // int -> ordered uint
      u64 p = ((u64)mono << 32) | (u32)bestc[qs];
#pragma unroll
      for (int sh = 1; sh < 16; sh <<= 1) {
        const u64 o = __shfl_xor(p, sh, 64);
        if (o > p) p = o;
      }
      if ((lane & 15) == 0) mrg[(rB2 + m * 16 + r) * 2 + wc] = p;
    }
  __syncthreads();
  if (tid < 256) {
    const u64 p0 = mrg[tid * 2], p1 = mrg[tid * 2 + 1];
    best_out[(size_t)(rowBase + tid) * NSPLIT + split] = p0 > p1 ? p0 : p1;
  }
}

// ---------- kernel 3: merge splits, exact fp32 distance + log ----------

__global__ __launch_bounds__(256) void k_dist(
    const float* __restrict__ x, const float* __restrict__ norms,
    const u64* __restrict__ best, float* __restrict__ logd) {
  const int w = threadIdx.x >> 6, lane = threadIdx.x & 63;
  const int i = blockIdx.x * 4 + w;
  u64 p = 0;
#pragma unroll
  for (int s = 0; s < NSPLIT; ++s) {
    const u64 qq = best[(size_t)i * NSPLIT + s];
    if (qq > p) p = qq;
  }
  const int j = (int)(p & 0xffffffffu);
  const float invi = 1.f / fmaxf(norms[i], EPSF);
  const float invj = 1.f / fmaxf(norms[j], EPSF);
  const float4* xi = (const float4*)(x + (size_t)i * D);
  const float4* xj = (const float4*)(x + (size_t)j * D);
  float s = 0.f;
#pragma unroll
  for (int t = 0; t < 4; ++t) {
    const float4 a = xi[lane + t * 64], b = xj[lane + t * 64];
    float d;
    d = a.x * invi - b.x * invj + EPSF; s += d * d;
    d = a.y * invi - b.y * invj + EPSF; s += d * d;
    d = a.z * invi - b.z * invj + EPSF; s += d * d;
    d = a.w * invi - b.w * invj + EPSF; s += d * d;
  }
#pragma unroll
  for (int sh = 32; sh; sh >>= 1) s += __shfl_xor(s, sh, 64);
  if (lane == 0) logd[i] = logf(sqrtf(s) + EPSF);
}

// ---------- kernel 4: deterministic fixed-order mean ----------

__global__ __launch_bounds__(256) void k_final(const float* __restrict__ logd,
                                               float* __restrict__ out) {
  __shared__ double red[256];
  double s = 0.0;
  for (int i = threadIdx.x; i < N; i += 256) s += (double)logd[i];
  red[threadIdx.x] = s;
  __syncthreads();
  for (int sh = 128; sh; sh >>= 1) {
    if ((int)threadIdx.x < sh) red[threadIdx.x] += red[threadIdx.x + sh];
    __syncthreads();
  }
  if (threadIdx.x == 0) out[0] = (float)(-red[0] / (double)N);
}

// ---------- launch ----------

extern "C" void kernel_launch(void* const* d_in, const int* in_sizes, int n_in,
                              void* d_out, int out_size, void* d_ws,
                              size_t ws_size, hipStream_t stream) {
  const float* x = (const float*)d_in[0];
  float* out = (float*)d_out;
  char* ws = (char*)d_ws;

  // ws: xq 16MB | norms 64KB | best 512KB | logd 64KB
  signed char* xq = (signed char*)ws;
  float* norms = (float*)(ws + 16777216);
  u64* best = (u64*)(ws + 16842752);
  float* logd = (float*)(ws + 17367040);

  k_normalize<<<N / 4, 256, 0, stream>>>(x, xq, norms);
  k_argmax<<<64 * NSPLIT, 512, LDS_TOT, stream>>>(xq, best);
  k_dist<<<N / 4, 256, 0, stream>>>(x, norms, best, logd);
  k_final<<<1, 256, 0, stream>>>(logd, out);
}